// Round 6
// baseline (283.774 us; speedup 1.0000x reference)
//
#include <hip/hip_runtime.h>
#include <math.h>

#define L    1024
#define D    256
#define NCH  3
#define HEADS 32      // B*N
#define EDIM 112
#define BATCH 4

typedef __bf16 bf8_t __attribute__((ext_vector_type(8)));
typedef float  f4_t  __attribute__((ext_vector_type(4)));

typedef __attribute__((address_space(1))) const void GVC;
typedef __attribute__((address_space(3))) void LDSV;

// RNE float->bf16
__device__ inline unsigned short f2bf(float x) {
    unsigned u = __float_as_uint(x);
    u += 0x7FFFu + ((u >> 16) & 1u);
    return (unsigned short)(u >> 16);
}
__device__ inline float bf2f(unsigned short h) {
    return __uint_as_float(((unsigned)h) << 16);
}

// ---------------- fused prologue: pe_d table + edge + xs -------------------
__global__ void prep_kernel(const float* __restrict__ edge, const float* __restrict__ xi,
                            float* __restrict__ pe_d, float* __restrict__ eout,
                            float* __restrict__ xsb)
{
    int idx = blockIdx.x * blockDim.x + threadIdx.x;
    if (idx < L * D) {
        int l = idx >> 8, i = idx & (D - 1);
        float expo = (float)(i & ~1) * (1.0f / (float)D);
        float ang = (float)l * __powf(10000.0f, -expo);
        pe_d[idx] = (i & 1) ? cosf(ang) : sinf(ang);
    } else if (idx < L * D + BATCH * L * EDIM) {
        int j = idx - L * D;
        int i = j % EDIM;
        int l = (j / EDIM) % L;
        float expo = (float)(i & ~1) * (1.0f / (float)EDIM);
        float ang = (float)l * __powf(10000.0f, -expo);
        eout[j] = edge[j] + ((i & 1) ? cosf(ang) : sinf(ang));
    } else {
        int j = idx - (L * D + BATCH * L * EDIM);
        if (j < HEADS * L * NCH) {
            int c = j % 3;
            int l = (j / 3) & (L - 1);
            float ang = (c == 2) ? (float)l * 0.0021544347f : (float)l;  // 10000^(-2/3)
            float pe = (c == 1) ? cosf(ang) : sinf(ang);
            xsb[j] = xi[j] + pe;
        }
    }
}

// ---------------- split pass: (theta+pe) -> hi/lo bf16; W -> bf16 ----------
// Output in FRAGMENT-MAJOR layout: unit t=(g,u,r) stored at t*8, where
// g=row/16, u=k/8, r=row%16. One MFMA fragment group (16 rows x 8 k) is a
// contiguous 1KB span -> qkv stages it with ONE global_load_lds per chunk and
// reads each fragment as a conflict-free ds_read_b128 (no swizzle needed).
// R5 lesson: PE from table (pe_d), not per-element transcendentals.
__global__ void split_kernel(const float* __restrict__ theta, const float* __restrict__ pe_d,
                             const float* __restrict__ Wq, const float* __restrict__ Wk,
                             const float* __restrict__ Wv,
                             unsigned short* __restrict__ xhi, unsigned short* __restrict__ xlo,
                             unsigned short* __restrict__ whb)
{
    int idx = blockIdx.x * blockDim.x + threadIdx.x;
    if (idx < HEADS * L * (D / 8)) {          // 1,048,576 X units
        int g = idx >> 9, u = (idx >> 4) & 31, r = idx & 15;
        int row = g * 16 + r;
        int l = row & (L - 1);
        int k0 = u * 8;
        const float4* tp = reinterpret_cast<const float4*>(&theta[(size_t)row * D + k0]);
        const float4* pp = reinterpret_cast<const float4*>(&pe_d[(size_t)l * D + k0]);
        float4 a = tp[0], b = tp[1], pa = pp[0], pb = pp[1];
        float x[8] = {a.x + pa.x, a.y + pa.y, a.z + pa.z, a.w + pa.w,
                      b.x + pb.x, b.y + pb.y, b.z + pb.z, b.w + pb.w};
        union { unsigned short us[8]; float4 f4; } hi, lo;
        #pragma unroll
        for (int j = 0; j < 8; j++) {
            unsigned short h = f2bf(x[j]);
            hi.us[j] = h;
            lo.us[j] = f2bf(x[j] - bf2f(h));
        }
        *reinterpret_cast<float4*>(&xhi[(size_t)idx * 8]) = hi.f4;
        *reinterpret_cast<float4*>(&xlo[(size_t)idx * 8]) = lo.f4;
    } else {
        int t2 = idx - HEADS * L * (D / 8);
        if (t2 < 3 * 256 * 32) {              // 24,576 W units
            int gw = t2 >> 9, u = (t2 >> 4) & 31, r = t2 & 15;
            int wrow = gw * 16 + r;           // 0..767 (Wq|Wk|Wv rows)
            const float* W = (wrow < 256) ? Wq : (wrow < 512) ? Wk : Wv;
            const float4* wp4 = reinterpret_cast<const float4*>(&W[(size_t)(wrow & 255) * D + u * 8]);
            float4 a = wp4[0], b = wp4[1];
            float x[8] = {a.x, a.y, a.z, a.w, b.x, b.y, b.z, b.w};
            union { unsigned short us[8]; float4 f4; } hv;
            #pragma unroll
            for (int j = 0; j < 8; j++) hv.us[j] = f2bf(x[j]);
            *reinterpret_cast<float4*>(&whb[(size_t)t2 * 8]) = hv.f4;
        }
    }
}

// ---------------- QKV projection: LDS-staged MFMA from pre-split bf16 ------
// R4+R5 synthesis: pre-split inputs (no conversion VALU) + global_load_lds
// tile staging (no per-wave L2 fabric re-fetch) + fragment-major layout
// (conflict-free b128 reads, contiguous 1KB stage chunks).
// kh stored PRE-SWIZZLED (e ^= (row&7)*8), vt PRE-SWIZZLED
// (us ^= ((e>>1)&3)*8) for attn's linear global_load_lds staging.
__global__ __launch_bounds__(256) void qkv_mfma(
    const unsigned short* __restrict__ xhi, const unsigned short* __restrict__ xlo,
    const unsigned short* __restrict__ whb,
    unsigned short* __restrict__ qh, unsigned short* __restrict__ ql,
    unsigned short* __restrict__ kh, unsigned short* __restrict__ vt)
{
    __shared__ __align__(16) unsigned short XHs[2][4096];  // 16KB X-hi dbuf
    __shared__ __align__(16) unsigned short XLs[2][4096];  // 16KB X-lo dbuf
    __shared__ __align__(16) unsigned short Wbs[2][4096];  // 16KB W dbuf

    int tid = threadIdx.x;
    int w = tid >> 6, lane = tid & 63;
    int quad = lane >> 4, l16 = lane & 15;
    int aoff = (w & 1) * 64, boff = (w >> 1) * 64;

    int b = blockIdx.x;                 // 0..1535
    int xcd = b & 7, r = b >> 3;        // r in 0..191
    int bx = r % 6;                     // selector (wsel, eBase)
    int rowPanel = (r / 6) * 8 + xcd;   // all 6 bx of a panel share xcd
    int rowBase = rowPanel * 128;
    int wsel = bx >> 1;
    int eBase = (bx & 1) * 128;

    const unsigned short* xh_p = xhi + (size_t)rowBase * D;
    const unsigned short* xl_p = xlo + (size_t)rowBase * D;
    const unsigned short* w_p  = whb + (size_t)(wsel * 256 + eBase) * D;

    f4_t acc[4][4];
    #pragma unroll
    for (int mi = 0; mi < 4; mi++)
        #pragma unroll
        for (int ni = 0; ni < 4; ni++) acc[mi][ni] = (f4_t){0.f, 0.f, 0.f, 0.f};

    // stage 24 x 1KB chunks (XH 8, XL 8, W 8) for k-tile kt into buffer buf
    auto stage = [&](int kt, int buf) {
        #pragma unroll
        for (int j = 0; j < 6; j++) {
            int c = w * 6 + j;              // wave-uniform chunk id
            int bsel = c >> 3, g = c & 7;
            const unsigned short* s = (bsel == 0) ? xh_p : (bsel == 1) ? xl_p : w_p;
            unsigned short* d = (bsel == 0) ? XHs[buf] : (bsel == 1) ? XLs[buf] : Wbs[buf];
            __builtin_amdgcn_global_load_lds(
                (GVC*)(s + (size_t)g * 4096 + kt * 512 + lane * 8),
                (LDSV*)(d + g * 512), 16, 0, 0);
        }
    };

    stage(0, 0);
    __syncthreads();

    #define FR(buf2d, g16) (*reinterpret_cast<const bf8_t*>(&(buf2d)[(g16) * 512 + quad * 128 + l16 * 8]))

    if (wsel < 2) {
        for (int kt = 0; kt < 8; kt++) {
            int buf = kt & 1;
            if (kt < 7) stage(kt + 1, buf ^ 1);
            bf8_t aw[4], bxh[4], bxl[4];
            #pragma unroll
            for (int mi = 0; mi < 4; mi++)
                aw[mi] = FR(Wbs[buf], (aoff >> 4) + mi);
            #pragma unroll
            for (int ni = 0; ni < 4; ni++) {
                bxh[ni] = FR(XHs[buf], (boff >> 4) + ni);
                bxl[ni] = FR(XLs[buf], (boff >> 4) + ni);
            }
            #pragma unroll
            for (int ni = 0; ni < 4; ni++)
                #pragma unroll
                for (int mi = 0; mi < 4; mi++) {
                    acc[mi][ni] = __builtin_amdgcn_mfma_f32_16x16x32_bf16(aw[mi], bxh[ni], acc[mi][ni], 0, 0, 0);
                    acc[mi][ni] = __builtin_amdgcn_mfma_f32_16x16x32_bf16(aw[mi], bxl[ni], acc[mi][ni], 0, 0, 0);
                }
            __syncthreads();
        }
        float scale = (wsel == 0) ? 0.0625f : 1.0f;  // fold 1/sqrt(d) into q
        #pragma unroll
        for (int mi = 0; mi < 4; mi++) {
            #pragma unroll
            for (int ni = 0; ni < 4; ni++) {
                int e0 = eBase + aoff + mi * 16 + quad * 4;
                size_t row = rowBase + boff + ni * 16 + l16;
                union { unsigned short us[4]; unsigned long long u; } ph, pl;
                #pragma unroll
                for (int rr = 0; rr < 4; rr++) {
                    float x = acc[mi][ni][rr] * scale;
                    unsigned short h = f2bf(x);
                    ph.us[rr] = h;
                    pl.us[rr] = f2bf(x - bf2f(h));
                }
                if (wsel == 0) {
                    *reinterpret_cast<unsigned long long*>(&qh[row * D + e0]) = ph.u;
                    *reinterpret_cast<unsigned long long*>(&ql[row * D + e0]) = pl.u;
                } else {
                    int e0s = e0 ^ ((l16 & 7) << 3);   // row&7 == l16&7
                    *reinterpret_cast<unsigned long long*>(&kh[row * D + e0s]) = ph.u;
                }
            }
        }
    } else {
        for (int kt = 0; kt < 8; kt++) {
            int buf = kt & 1;
            if (kt < 7) stage(kt + 1, buf ^ 1);
            bf8_t axh[4], axl[4], bw[4];
            #pragma unroll
            for (int mi = 0; mi < 4; mi++) {
                axh[mi] = FR(XHs[buf], (aoff >> 4) + mi);
                axl[mi] = FR(XLs[buf], (aoff >> 4) + mi);
            }
            #pragma unroll
            for (int ni = 0; ni < 4; ni++)
                bw[ni] = FR(Wbs[buf], (boff >> 4) + ni);
            #pragma unroll
            for (int ni = 0; ni < 4; ni++)
                #pragma unroll
                for (int mi = 0; mi < 4; mi++) {
                    acc[mi][ni] = __builtin_amdgcn_mfma_f32_16x16x32_bf16(axh[mi], bw[ni], acc[mi][ni], 0, 0, 0);
                    acc[mi][ni] = __builtin_amdgcn_mfma_f32_16x16x32_bf16(axl[mi], bw[ni], acc[mi][ni], 0, 0, 0);
                }
            __syncthreads();
        }
        #pragma unroll
        for (int mi = 0; mi < 4; mi++) {
            #pragma unroll
            for (int ni = 0; ni < 4; ni++) {
                int row0 = rowBase + aoff + mi * 16 + quad * 4;
                int e = eBase + boff + ni * 16 + l16;
                int head = row0 >> 10, kb = (row0 & 1023) >> 5, kk = row0 & 31;
                union { unsigned short us[4]; unsigned long long u; } pk;
                #pragma unroll
                for (int rr = 0; rr < 4; rr++) pk.us[rr] = f2bf(acc[mi][ni][rr]);
                int us_sw = (e * 32 + kk) ^ (((e >> 1) & 3) << 3);  // V-tile swizzle
                *reinterpret_cast<unsigned long long*>(
                    &vt[((size_t)(head * 32 + kb)) * 8192 + us_sw]) = pk.u;
            }
        }
    }
    #undef FR
}

// ---------------- LDS-shared MFMA flash attention --------------------------
// Block (head,s): 8 mirrored units {4s..4s+3, 63-4s..60-4s}; stages
// Ts = 32-2s K/V tiles via global_load_lds (double-buffered), shared by all
// 8 waves -> fabric traffic /5 vs per-wave fetch. (R4: confirmed, ~110->~40us)
__device__ __forceinline__ void stage_tile(
    const unsigned short* kht, const unsigned short* vtt,
    unsigned short* Ks, unsigned short* Vs, int kt, int buf, int w, int lane)
{
    #pragma unroll
    for (int i = 0; i < 2; i++) {
        int ch = w * 2 + i;   // wave-uniform chunk id (LDS base must be uniform)
        __builtin_amdgcn_global_load_lds(
            (GVC*)(kht + (size_t)kt * 8192 + ch * 512 + lane * 8),
            (LDSV*)(Ks + buf * 8192 + ch * 512), 16, 0, 0);
        __builtin_amdgcn_global_load_lds(
            (GVC*)(vtt + (size_t)kt * 8192 + ch * 512 + lane * 8),
            (LDSV*)(Vs + buf * 8192 + ch * 512), 16, 0, 0);
    }
}

__global__ __launch_bounds__(512) void attn_v7(
    const unsigned short* __restrict__ qh, const unsigned short* __restrict__ ql,
    const unsigned short* __restrict__ kh, const unsigned short* __restrict__ vt,
    float* __restrict__ hout)
{
    __shared__ __align__(16) unsigned short Ks[2 * 8192];   // 32KB K dbuf
    __shared__ __align__(16) unsigned short Vs[2 * 8192];   // 32KB V dbuf
    __shared__ __align__(16) unsigned short Pb[8][16 * 40]; // 10KB P
    __shared__ unsigned short lds_pad[4200];                // >80KB: 1 block/CU

    int tid = threadIdx.x;
    int w = tid >> 6, lane = tid & 63;
    int quad = lane >> 4, l16 = lane & 15;
    int b = blockIdx.x;
    int head = ((b & 7) << 2) + (b >> 6);     // 4 heads per XCD share L2
    int s = (b >> 3) & 7;
    int u = (w < 4) ? (4 * s + w) : (63 - 4 * s - (w - 4));  // mirrored units
    int Ts = 32 - 2 * s;
    int lim = u >> 1;
    size_t hb = (size_t)head * (L * D);
    const unsigned short* kht = kh + hb;
    const unsigned short* vtt = vt + (size_t)head * (32 * 8192);
    unsigned short* Pw = Pb[w];

    if (hout == nullptr) lds_pad[tid] = 1;    // opaque: keep pad allocated

    int q_g = u * 16 + l16;

    // Q fragments in registers for the whole kernel; asm keep-alive stops
    // the scheduler from sinking/re-fetching them inside the k-loop.
    f4_t qfh[8], qfl[8];
    {
        const unsigned short* ph = qh + hb + (size_t)q_g * D + quad * 8;
        const unsigned short* pl = ql + hb + (size_t)q_g * D + quad * 8;
        #pragma unroll
        for (int c = 0; c < 8; c++) {
            qfh[c] = *reinterpret_cast<const f4_t*>(ph + c * 32);
            qfl[c] = *reinterpret_cast<const f4_t*>(pl + c * 32);
        }
    }
    #pragma unroll
    for (int c = 0; c < 8; c++) {
        asm volatile("" : "+v"(qfh[c]));
        asm volatile("" : "+v"(qfl[c]));
    }

    stage_tile(kht, vtt, Ks, Vs, 0, 0, w, lane);

    f4_t acc[16];
    #pragma unroll
    for (int i = 0; i < 16; i++) acc[i] = (f4_t){0.f, 0.f, 0.f, 0.f};
    float mrun = -1e30f, lrun = 0.f;

    int xm = (l16 & 7) << 3;                        // K e-swizzle (us)
    int vq = (quad * 8) ^ (((l16 >> 1) & 3) << 3);  // V swizzled col base

    asm volatile("s_waitcnt vmcnt(0)" ::: "memory");
    __syncthreads();

    #pragma unroll 1
    for (int kt = 0; kt < Ts; kt++) {
        if (kt + 1 < Ts)
            stage_tile(kht, vtt, Ks, Vs, kt + 1, (kt + 1) & 1, w, lane);

        if (kt <= lim) {   // wave-uniform predicate
            const unsigned short* Kb = Ks + (kt & 1) * 8192;
            const unsigned short* Vb = Vs + (kt & 1) * 8192;
            int kBase = kt * 32;

            bf8_t kf0[8], kf1[8];
            #pragma unroll
            for (int c = 0; c < 8; c++) {
                int col = (quad * 8 + c * 32) ^ xm;
                kf0[c] = *reinterpret_cast<const bf8_t*>(&Kb[l16 * 256 + col]);
                kf1[c] = *reinterpret_cast<const bf8_t*>(&Kb[(16 + l16) * 256 + col]);
            }
            // V batch A: LDS-read latency hides under the QK MFMAs
            const unsigned short* vpb = Vb + l16 * 32 + vq;
            bf8_t vfA[8];
            #pragma unroll
            for (int dt = 0; dt < 8; dt++)
                vfA[dt] = *reinterpret_cast<const bf8_t*>(vpb + dt * 512);

            // dual accumulator chains: halves dependent-MFMA depth
            f4_t s0a = (f4_t){0.f,0.f,0.f,0.f}, s0b = (f4_t){0.f,0.f,0.f,0.f};
            f4_t s1a = (f4_t){0.f,0.f,0.f,0.f}, s1b = (f4_t){0.f,0.f,0.f,0.f};
            #pragma unroll
            for (int c = 0; c < 8; c += 2) {
                s0a = __builtin_amdgcn_mfma_f32_16x16x32_bf16(kf0[c],     __builtin_bit_cast(bf8_t, qfh[c]),     s0a, 0, 0, 0);
                s0b = __builtin_amdgcn_mfma_f32_16x16x32_bf16(kf0[c + 1], __builtin_bit_cast(bf8_t, qfh[c + 1]), s0b, 0, 0, 0);
                s0a = __builtin_amdgcn_mfma_f32_16x16x32_bf16(kf0[c],     __builtin_bit_cast(bf8_t, qfl[c]),     s0a, 0, 0, 0);
                s0b = __builtin_amdgcn_mfma_f32_16x16x32_bf16(kf0[c + 1], __builtin_bit_cast(bf8_t, qfl[c + 1]), s0b, 0, 0, 0);
            }
            #pragma unroll
            for (int c = 0; c < 8; c += 2) {
                s1a = __builtin_amdgcn_mfma_f32_16x16x32_bf16(kf1[c],     __builtin_bit_cast(bf8_t, qfh[c]),     s1a, 0, 0, 0);
                s1b = __builtin_amdgcn_mfma_f32_16x16x32_bf16(kf1[c + 1], __builtin_bit_cast(bf8_t, qfh[c + 1]), s1b, 0, 0, 0);
                s1a = __builtin_amdgcn_mfma_f32_16x16x32_bf16(kf1[c],     __builtin_bit_cast(bf8_t, qfl[c]),     s1a, 0, 0, 0);
                s1b = __builtin_amdgcn_mfma_f32_16x16x32_bf16(kf1[c + 1], __builtin_bit_cast(bf8_t, qfl[c + 1]), s1b, 0, 0, 0);
            }
            f4_t sc[2];
            sc[0] = s0a + s0b;
            sc[1] = s1a + s1b;

            // causal mask + per-lane softmax over 8 keys, quad-pair reduce
            float pv[2][4];
            float tm = -1e30f;
            #pragma unroll
            for (int t = 0; t < 2; t++)
                #pragma unroll
                for (int rr = 0; rr < 4; rr++) {
                    int key = kBase + t * 16 + quad * 4 + rr;
                    float sv = (key <= q_g) ? sc[t][rr] : -1e30f;
                    sc[t][rr] = sv;
                    tm = fmaxf(tm, sv);
                }
            tm = fmaxf(tm, __shfl_xor(tm, 16));
            tm = fmaxf(tm, __shfl_xor(tm, 32));
            bool grow = __any(tm > mrun);      // alpha==1 exactly if false
            float mnew = fmaxf(mrun, tm);
            float alpha = grow ? __expf(mrun - mnew) : 1.0f;
            mrun = mnew;
            float ts = 0.f;
            #pragma unroll
            for (int t = 0; t < 2; t++)
                #pragma unroll
                for (int rr = 0; rr < 4; rr++) {
                    float p = __expf(sc[t][rr] - mnew);
                    pv[t][rr] = p;
                    ts += p;
                }
            ts += __shfl_xor(ts, 16);
            ts += __shfl_xor(ts, 32);
            lrun = lrun * alpha + ts;

            // P write before O-rescale: LDS round-trip hides under the muls
            #pragma unroll
            for (int t = 0; t < 2; t++) {
                union { unsigned short us[4]; unsigned long long uu; } pk;
                #pragma unroll
                for (int rr = 0; rr < 4; rr++) pk.us[rr] = f2bf(pv[t][rr]);
                *reinterpret_cast<unsigned long long*>(&Pw[l16 * 40 + t * 16 + quad * 4]) = pk.uu;
            }
            // V batch B
            bf8_t vfB[8];
            #pragma unroll
            for (int dt = 0; dt < 8; dt++)
                vfB[dt] = *reinterpret_cast<const bf8_t*>(vpb + (8 + dt) * 512);
            if (grow) {
                #pragma unroll
                for (int dt = 0; dt < 16; dt++) acc[dt] *= alpha;
            }
            asm volatile("s_waitcnt lgkmcnt(0)" ::: "memory");
            bf8_t pf = *reinterpret_cast<const bf8_t*>(&Pw[l16 * 40 + quad * 8]);
            #pragma unroll
            for (int dt = 0; dt < 8; dt++)
                acc[dt] = __builtin_amdgcn_mfma_f32_16x16x32_bf16(vfA[dt], pf, acc[dt], 0, 0, 0);
            #pragma unroll
            for (int dt = 0; dt < 8; dt++)
                acc[8 + dt] = __builtin_amdgcn_mfma_f32_16x16x32_bf16(vfB[dt], pf, acc[8 + dt], 0, 0, 0);
        }

        asm volatile("s_waitcnt vmcnt(0)" ::: "memory");
        __syncthreads();
    }

    float inv = 1.f / lrun;
    float* dst = hout + hb + (size_t)q_g * D + quad * 4;
    #pragma unroll
    for (int dt = 0; dt < 16; dt++) {
        float4 o = {acc[dt][0] * inv, acc[dt][1] * inv,
                    acc[dt][2] * inv, acc[dt][3] * inv};
        *reinterpret_cast<float4*>(dst + dt * 16) = o;
    }
}

// ---------------- equivariant path: one wave per q row ---------------------
__global__ __launch_bounds__(256) void equiv_kernel(
    const float* __restrict__ xsb, float* __restrict__ xout)
{
    __shared__ float xs[L * NCH];
    int head = blockIdx.y;
    int tid = threadIdx.x;
    const float4* src = reinterpret_cast<const float4*>(xsb + (size_t)head * L * NCH);
    #pragma unroll
    for (int it = 0; it < 3; it++)
        reinterpret_cast<float4*>(xs)[tid + it * 256] = src[tid + it * 256];
    __syncthreads();

    int w = tid >> 6, lane = tid & 63;
    int q = blockIdx.x * 4 + w;
    float xq0 = xs[q * 3 + 0], xq1 = xs[q * 3 + 1], xq2 = xs[q * 3 + 2];

    float m = 0.f;
    for (int k = lane; k < q; k += 64) {
        float d0 = xq0 - xs[k * 3 + 0];
        float d1 = xq1 - xs[k * 3 + 1];
        float d2 = xq2 - xs[k * 3 + 2];
        m = fmaxf(m, d0 * d0 + d1 * d1 + d2 * d2);
    }
    #pragma unroll
    for (int off = 1; off < 64; off <<= 1) m = fmaxf(m, __shfl_xor(m, off));

    float s0 = 0.f, s1 = 0.f, s2 = 0.f, sn = 0.f;
    for (int k = lane; k < q; k += 64) {
        float d0 = xq0 - xs[k * 3 + 0];
        float d1 = xq1 - xs[k * 3 + 1];
        float d2 = xq2 - xs[k * 3 + 2];
        float wgt = __expf(d0 * d0 + d1 * d1 + d2 * d2 - m);
        sn += wgt;
        s0 += wgt * xs[k * 3 + 0];
        s1 += wgt * xs[k * 3 + 1];
        s2 += wgt * xs[k * 3 + 2];
    }
    #pragma unroll
    for (int off = 1; off < 64; off <<= 1) {
        sn += __shfl_xor(sn, off);
        s0 += __shfl_xor(s0, off);
        s1 += __shfl_xor(s1, off);
        s2 += __shfl_xor(s2, off);
    }
    float Z = sn + __expf(-m);
    float inv = 0.5f / Z;
    if (lane == 0) {
        size_t ob = (size_t)head * L * NCH + (size_t)q * NCH;
        xout[ob + 0] = xq0 + inv * (s0 - sn * xq0);
        xout[ob + 1] = xq1 + inv * (s1 - sn * xq1);
        xout[ob + 2] = xq2 + inv * (s2 - sn * xq2);
    }
}

extern "C" void kernel_launch(void* const* d_in, const int* in_sizes, int n_in,
                              void* d_out, int out_size, void* d_ws, size_t ws_size,
                              hipStream_t stream)
{
    (void)in_sizes; (void)n_in; (void)out_size; (void)ws_size;
    const float* theta = (const float*)d_in[0];
    const float* xi    = (const float*)d_in[1];
    const float* edge  = (const float*)d_in[2];
    const float* Wq    = (const float*)d_in[3];
    const float* Wk    = (const float*)d_in[4];
    const float* Wv    = (const float*)d_in[5];

    float* out  = (float*)d_out;
    float* hout = out;
    float* xout = out + 8388608;
    float* eout = out + 8388608 + 98304;

    const size_t NE = 8388608;
    unsigned short* base = (unsigned short*)d_ws;
    unsigned short* qh  = base;
    unsigned short* ql  = base + NE;
    unsigned short* kh  = base + 2 * NE;
    unsigned short* vt  = base + 3 * NE;
    unsigned short* xhi = base + 4 * NE;
    unsigned short* xlo = base + 5 * NE;
    unsigned short* whb = base + 6 * NE;                   // 196608 us
    float* pe_d = (float*)(base + 6 * NE + 196608);        // 1024*256 floats
    float* xsb  = pe_d + L * D;                            // 32*1024*3 floats

    prep_kernel<<<3200, 256, 0, stream>>>(edge, xi, pe_d, eout, xsb);
    split_kernel<<<4192, 256, 0, stream>>>(theta, pe_d, Wq, Wk, Wv, xhi, xlo, whb);
    equiv_kernel<<<dim3(L / 4, HEADS), 256, 0, stream>>>(xsb, xout);
    qkv_mfma<<<1536, 256, 0, stream>>>(xhi, xlo, whb, qh, ql, kh, vt);
    attn_v7<<<256, 512, 0, stream>>>(qh, ql, kh, vt, hout);
}

// Round 7
// 245.491 us; speedup vs baseline: 1.1559x; 1.1559x over previous
//
#include <hip/hip_runtime.h>
#include <math.h>

#define L    1024
#define D    256
#define NCH  3
#define HEADS 32      // B*N
#define EDIM 112
#define BATCH 4

typedef __bf16 bf8_t __attribute__((ext_vector_type(8)));
typedef float  f4_t  __attribute__((ext_vector_type(4)));

typedef __attribute__((address_space(1))) const void GVC;
typedef __attribute__((address_space(3))) void LDSV;

// RNE float->bf16
__device__ inline unsigned short f2bf(float x) {
    unsigned u = __float_as_uint(x);
    u += 0x7FFFu + ((u >> 16) & 1u);
    return (unsigned short)(u >> 16);
}
__device__ inline float bf2f(unsigned short h) {
    return __uint_as_float(((unsigned)h) << 16);
}

// ------- fused prologue: pe_d table + edge + xs + whb (frag-major bf16) ----
__global__ void prep_kernel(const float* __restrict__ edge, const float* __restrict__ xi,
                            const float* __restrict__ Wq, const float* __restrict__ Wk,
                            const float* __restrict__ Wv,
                            float* __restrict__ pe_d, float* __restrict__ eout,
                            float* __restrict__ xsb, unsigned short* __restrict__ whb)
{
    int idx = blockIdx.x * blockDim.x + threadIdx.x;
    if (idx < L * D) {
        int l = idx >> 8, i = idx & (D - 1);
        float expo = (float)(i & ~1) * (1.0f / (float)D);
        float ang = (float)l * __powf(10000.0f, -expo);
        pe_d[idx] = (i & 1) ? cosf(ang) : sinf(ang);
    } else if (idx < L * D + BATCH * L * EDIM) {
        int j = idx - L * D;
        int i = j % EDIM;
        int l = (j / EDIM) % L;
        float expo = (float)(i & ~1) * (1.0f / (float)EDIM);
        float ang = (float)l * __powf(10000.0f, -expo);
        eout[j] = edge[j] + ((i & 1) ? cosf(ang) : sinf(ang));
    } else if (idx < L * D + BATCH * L * EDIM + HEADS * L * NCH) {
        int j = idx - (L * D + BATCH * L * EDIM);
        int c = j % 3;
        int l = (j / 3) & (L - 1);
        float ang = (c == 2) ? (float)l * 0.0021544347f : (float)l;  // 10000^(-2/3)
        float pe = (c == 1) ? cosf(ang) : sinf(ang);
        xsb[j] = xi[j] + pe;
    } else {
        int j = idx - (L * D + BATCH * L * EDIM + HEADS * L * NCH);
        if (j < 3 * 8192) {                       // W -> bf16, fragment-major
            int wsel = j >> 13;
            int t = j & 8191;
            int g = t >> 9, u = (t >> 4) & 31, rr = t & 15;
            const float* W = (wsel == 0) ? Wq : (wsel == 1) ? Wk : Wv;
            const float4* s = reinterpret_cast<const float4*>(&W[(size_t)(g * 16 + rr) * D + u * 8]);
            float4 a = s[0], b = s[1];
            float x[8] = {a.x, a.y, a.z, a.w, b.x, b.y, b.z, b.w};
            union { unsigned short us[8]; float4 f4; } hv;
            #pragma unroll
            for (int q = 0; q < 8; q++) hv.us[q] = f2bf(x[q]);
            *reinterpret_cast<float4*>(&whb[(size_t)wsel * 65536 + g * 4096 + u * 128 + rr * 8]) = hv.f4;
        }
    }
}

// ---------------- QKV projection: 768-block, full-width output -------------
// R4-R6 synthesis: X converted IN-KERNEL (no HBM intermediate — R6 lesson)
// but only 3x total (768 = panel x wsel blocks, full 256-wide output each;
// was 6x), W pre-converted in prep and staged via global_load_lds (dbuf),
// fragment-major LDS (wave-contiguous 1KB b128 reads/writes = 0 conflicts),
// 64 MFMAs per barrier interval (was 32). Conversion VALU overlaps MFMA.
// kh stored PRE-SWIZZLED (e ^= (row&7)*8), vt PRE-SWIZZLED
// (us ^= ((e>>1)&3)*8) for attn's linear global_load_lds staging.
__global__ __launch_bounds__(256) void qkv_mfma(
    const float* __restrict__ theta, const float* __restrict__ pe_d,
    const unsigned short* __restrict__ whb,
    unsigned short* __restrict__ qh, unsigned short* __restrict__ ql,
    unsigned short* __restrict__ kh, unsigned short* __restrict__ vt)
{
    __shared__ __align__(16) unsigned short XsH[2][4096];  // 16KB X-hi dbuf
    __shared__ __align__(16) unsigned short XsL[2][4096];  // 16KB X-lo dbuf
    __shared__ __align__(16) unsigned short Ws[2][8192];   // 32KB W dbuf

    int tid = threadIdx.x;
    int w = tid >> 6, lane = tid & 63;
    int quad = lane >> 4, l16 = lane & 15;

    int b = blockIdx.x;                 // 0..767
    int xcd = b & 7, r = b >> 3;        // r 0..95
    int wsel = r % 3;
    int panel = (r / 3) * 8 + xcd;      // all 3 wsel of a panel share an XCD
    int rowBase = panel * 128;
    const unsigned short* wsrc = whb + (size_t)wsel * 65536;

    // conversion slot: thread -> (row sr, k-half ks) of the 128x32 X tile
    int sr = tid >> 1;
    int ks = (tid & 1) * 16;
    int cg = sr >> 4, cr = sr & 15, cu = ks >> 3;
    int xoff = cg * 512 + cu * 128 + cr * 8;     // fragment-major elem offset

    const float* tp_base = &theta[(size_t)(rowBase + sr) * D + ks];
    const float* pp_base = &pe_d[(size_t)((rowBase + sr) & (L - 1)) * D + ks];

    int wg8 = (w >> 1) * 8;             // wave's e-fragment base (8 frags)
    int wg4 = (w & 1) * 4;              // wave's x-row fragment base (4 frags)

    f4_t acc[32];
    #pragma unroll
    for (int i = 0; i < 32; i++) acc[i] = (f4_t){0.f, 0.f, 0.f, 0.f};

    auto stageW = [&](int kt, int buf) {
        #pragma unroll
        for (int j = 0; j < 4; j++) {
            int g = w * 4 + j;          // wave-uniform chunk id
            __builtin_amdgcn_global_load_lds(
                (GVC*)(wsrc + (size_t)g * 4096 + kt * 512 + lane * 8),
                (LDSV*)(Ws[buf] + g * 512), 16, 0, 0);
        }
    };
    auto convX = [&](const float* xv, int buf) {
        union { unsigned short us[8]; float4 f4; } h0, l0, h1, l1;
        #pragma unroll
        for (int e = 0; e < 16; e++) {
            float v = xv[e];
            unsigned short h = f2bf(v);
            unsigned short lo = f2bf(v - bf2f(h));
            if (e < 8) { h0.us[e] = h; l0.us[e] = lo; }
            else       { h1.us[e - 8] = h; l1.us[e - 8] = lo; }
        }
        *reinterpret_cast<float4*>(&XsH[buf][xoff])       = h0.f4;
        *reinterpret_cast<float4*>(&XsH[buf][xoff + 128]) = h1.f4;
        *reinterpret_cast<float4*>(&XsL[buf][xoff])       = l0.f4;
        *reinterpret_cast<float4*>(&XsL[buf][xoff + 128]) = l1.f4;
    };

    // prologue: tile 0
    {
        float xv[16];
        #pragma unroll
        for (int j = 0; j < 4; j++) {
            float4 tv = reinterpret_cast<const float4*>(tp_base)[j];
            float4 pv = reinterpret_cast<const float4*>(pp_base)[j];
            xv[j * 4 + 0] = tv.x + pv.x; xv[j * 4 + 1] = tv.y + pv.y;
            xv[j * 4 + 2] = tv.z + pv.z; xv[j * 4 + 3] = tv.w + pv.w;
        }
        convX(xv, 0);
        stageW(0, 0);
    }
    __syncthreads();

    #define FR(buf2d, g16) (*reinterpret_cast<const bf8_t*>(&(buf2d)[(g16) * 512 + quad * 128 + l16 * 8]))

    for (int kt = 0; kt < 8; kt++) {
        int buf = kt & 1;

        // issue next-tile theta/pe loads early; waitcnt lands after MFMAs
        float xnv[16];
        if (kt < 7) {
            const float* tp = tp_base + (kt + 1) * 32;
            const float* pp = pp_base + (kt + 1) * 32;
            #pragma unroll
            for (int j = 0; j < 4; j++) {
                float4 tv = reinterpret_cast<const float4*>(tp)[j];
                float4 pv = reinterpret_cast<const float4*>(pp)[j];
                xnv[j * 4 + 0] = tv.x + pv.x; xnv[j * 4 + 1] = tv.y + pv.y;
                xnv[j * 4 + 2] = tv.z + pv.z; xnv[j * 4 + 3] = tv.w + pv.w;
            }
        }

        bf8_t bxh[4], bxl[4];
        #pragma unroll
        for (int mx = 0; mx < 4; mx++) {
            bxh[mx] = FR(XsH[buf], wg4 + mx);
            bxl[mx] = FR(XsL[buf], wg4 + mx);
        }

        if (wsel < 2) {
            #pragma unroll
            for (int ne = 0; ne < 8; ne++) {
                bf8_t aw = FR(Ws[buf], wg8 + ne);
                #pragma unroll
                for (int mx = 0; mx < 4; mx++) {
                    acc[ne * 4 + mx] = __builtin_amdgcn_mfma_f32_16x16x32_bf16(aw, bxh[mx], acc[ne * 4 + mx], 0, 0, 0);
                    acc[ne * 4 + mx] = __builtin_amdgcn_mfma_f32_16x16x32_bf16(aw, bxl[mx], acc[ne * 4 + mx], 0, 0, 0);
                }
            }
        } else {
            #pragma unroll
            for (int ne = 0; ne < 8; ne++) {
                bf8_t bw = FR(Ws[buf], wg8 + ne);
                #pragma unroll
                for (int mx = 0; mx < 4; mx++) {
                    acc[mx * 8 + ne] = __builtin_amdgcn_mfma_f32_16x16x32_bf16(bxh[mx], bw, acc[mx * 8 + ne], 0, 0, 0);
                    acc[mx * 8 + ne] = __builtin_amdgcn_mfma_f32_16x16x32_bf16(bxl[mx], bw, acc[mx * 8 + ne], 0, 0, 0);
                }
            }
        }

        if (kt < 7) {
            convX(xnv, buf ^ 1);        // VALU; overlaps MFMA pipe
            stageW(kt + 1, buf ^ 1);
        }
        __syncthreads();
    }
    #undef FR

    // ---- epilogue ----
    if (wsel < 2) {
        float scale = (wsel == 0) ? 0.0625f : 1.0f;  // fold 1/sqrt(d) into q
        #pragma unroll
        for (int ne = 0; ne < 8; ne++) {
            #pragma unroll
            for (int mx = 0; mx < 4; mx++) {
                int e0 = (w >> 1) * 128 + ne * 16 + quad * 4;
                size_t row = rowBase + (w & 1) * 64 + mx * 16 + l16;
                union { unsigned short us[4]; unsigned long long u; } ph, pl;
                #pragma unroll
                for (int rr = 0; rr < 4; rr++) {
                    float x = acc[ne * 4 + mx][rr] * scale;
                    unsigned short h = f2bf(x);
                    ph.us[rr] = h;
                    pl.us[rr] = f2bf(x - bf2f(h));
                }
                if (wsel == 0) {
                    *reinterpret_cast<unsigned long long*>(&qh[row * D + e0]) = ph.u;
                    *reinterpret_cast<unsigned long long*>(&ql[row * D + e0]) = pl.u;
                } else {
                    int e0s = e0 ^ ((l16 & 7) << 3);   // row&7 == l16&7
                    *reinterpret_cast<unsigned long long*>(&kh[row * D + e0s]) = ph.u;
                }
            }
        }
    } else {
        #pragma unroll
        for (int mx = 0; mx < 4; mx++) {
            #pragma unroll
            for (int ne = 0; ne < 8; ne++) {
                int row0 = rowBase + (w & 1) * 64 + mx * 16 + quad * 4;
                int e = (w >> 1) * 128 + ne * 16 + l16;
                int head = row0 >> 10, kb = (row0 & 1023) >> 5, kk = row0 & 31;
                union { unsigned short us[4]; unsigned long long u; } pk;
                #pragma unroll
                for (int rr = 0; rr < 4; rr++) pk.us[rr] = f2bf(acc[mx * 8 + ne][rr]);
                int us_sw = (e * 32 + kk) ^ (((e >> 1) & 3) << 3);  // V-tile swizzle
                *reinterpret_cast<unsigned long long*>(
                    &vt[((size_t)(head * 32 + kb)) * 8192 + us_sw]) = pk.u;
            }
        }
    }
}

// ---------------- LDS-shared MFMA flash attention --------------------------
// Block (head,s): 8 mirrored units {4s..4s+3, 63-4s..60-4s}; stages
// Ts = 32-2s K/V tiles via global_load_lds (double-buffered), shared by all
// 8 waves -> fabric traffic /5 vs per-wave fetch. (R4: confirmed, ~110->~40us)
__device__ __forceinline__ void stage_tile(
    const unsigned short* kht, const unsigned short* vtt,
    unsigned short* Ks, unsigned short* Vs, int kt, int buf, int w, int lane)
{
    #pragma unroll
    for (int i = 0; i < 2; i++) {
        int ch = w * 2 + i;   // wave-uniform chunk id (LDS base must be uniform)
        __builtin_amdgcn_global_load_lds(
            (GVC*)(kht + (size_t)kt * 8192 + ch * 512 + lane * 8),
            (LDSV*)(Ks + buf * 8192 + ch * 512), 16, 0, 0);
        __builtin_amdgcn_global_load_lds(
            (GVC*)(vtt + (size_t)kt * 8192 + ch * 512 + lane * 8),
            (LDSV*)(Vs + buf * 8192 + ch * 512), 16, 0, 0);
    }
}

__global__ __launch_bounds__(512) void attn_v7(
    const unsigned short* __restrict__ qh, const unsigned short* __restrict__ ql,
    const unsigned short* __restrict__ kh, const unsigned short* __restrict__ vt,
    float* __restrict__ hout)
{
    __shared__ __align__(16) unsigned short Ks[2 * 8192];   // 32KB K dbuf
    __shared__ __align__(16) unsigned short Vs[2 * 8192];   // 32KB V dbuf
    __shared__ __align__(16) unsigned short Pb[8][16 * 40]; // 10KB P
    __shared__ unsigned short lds_pad[4200];                // >80KB: 1 block/CU

    int tid = threadIdx.x;
    int w = tid >> 6, lane = tid & 63;
    int quad = lane >> 4, l16 = lane & 15;
    int b = blockIdx.x;
    int head = ((b & 7) << 2) + (b >> 6);     // 4 heads per XCD share L2
    int s = (b >> 3) & 7;
    int u = (w < 4) ? (4 * s + w) : (63 - 4 * s - (w - 4));  // mirrored units
    int Ts = 32 - 2 * s;
    int lim = u >> 1;
    size_t hb = (size_t)head * (L * D);
    const unsigned short* kht = kh + hb;
    const unsigned short* vtt = vt + (size_t)head * (32 * 8192);
    unsigned short* Pw = Pb[w];

    if (hout == nullptr) lds_pad[tid] = 1;    // opaque: keep pad allocated

    int q_g = u * 16 + l16;

    // Q fragments in registers for the whole kernel; asm keep-alive stops
    // the scheduler from sinking/re-fetching them inside the k-loop.
    f4_t qfh[8], qfl[8];
    {
        const unsigned short* ph = qh + hb + (size_t)q_g * D + quad * 8;
        const unsigned short* pl = ql + hb + (size_t)q_g * D + quad * 8;
        #pragma unroll
        for (int c = 0; c < 8; c++) {
            qfh[c] = *reinterpret_cast<const f4_t*>(ph + c * 32);
            qfl[c] = *reinterpret_cast<const f4_t*>(pl + c * 32);
        }
    }
    #pragma unroll
    for (int c = 0; c < 8; c++) {
        asm volatile("" : "+v"(qfh[c]));
        asm volatile("" : "+v"(qfl[c]));
    }

    stage_tile(kht, vtt, Ks, Vs, 0, 0, w, lane);

    f4_t acc[16];
    #pragma unroll
    for (int i = 0; i < 16; i++) acc[i] = (f4_t){0.f, 0.f, 0.f, 0.f};
    float mrun = -1e30f, lrun = 0.f;

    int xm = (l16 & 7) << 3;                        // K e-swizzle (us)
    int vq = (quad * 8) ^ (((l16 >> 1) & 3) << 3);  // V swizzled col base

    asm volatile("s_waitcnt vmcnt(0)" ::: "memory");
    __syncthreads();

    #pragma unroll 1
    for (int kt = 0; kt < Ts; kt++) {
        if (kt + 1 < Ts)
            stage_tile(kht, vtt, Ks, Vs, kt + 1, (kt + 1) & 1, w, lane);

        if (kt <= lim) {   // wave-uniform predicate
            const unsigned short* Kb = Ks + (kt & 1) * 8192;
            const unsigned short* Vb = Vs + (kt & 1) * 8192;
            int kBase = kt * 32;

            bf8_t kf0[8], kf1[8];
            #pragma unroll
            for (int c = 0; c < 8; c++) {
                int col = (quad * 8 + c * 32) ^ xm;
                kf0[c] = *reinterpret_cast<const bf8_t*>(&Kb[l16 * 256 + col]);
                kf1[c] = *reinterpret_cast<const bf8_t*>(&Kb[(16 + l16) * 256 + col]);
            }
            // V batch A: LDS-read latency hides under the QK MFMAs
            const unsigned short* vpb = Vb + l16 * 32 + vq;
            bf8_t vfA[8];
            #pragma unroll
            for (int dt = 0; dt < 8; dt++)
                vfA[dt] = *reinterpret_cast<const bf8_t*>(vpb + dt * 512);

            // dual accumulator chains: halves dependent-MFMA depth
            f4_t s0a = (f4_t){0.f,0.f,0.f,0.f}, s0b = (f4_t){0.f,0.f,0.f,0.f};
            f4_t s1a = (f4_t){0.f,0.f,0.f,0.f}, s1b = (f4_t){0.f,0.f,0.f,0.f};
            #pragma unroll
            for (int c = 0; c < 8; c += 2) {
                s0a = __builtin_amdgcn_mfma_f32_16x16x32_bf16(kf0[c],     __builtin_bit_cast(bf8_t, qfh[c]),     s0a, 0, 0, 0);
                s0b = __builtin_amdgcn_mfma_f32_16x16x32_bf16(kf0[c + 1], __builtin_bit_cast(bf8_t, qfh[c + 1]), s0b, 0, 0, 0);
                s0a = __builtin_amdgcn_mfma_f32_16x16x32_bf16(kf0[c],     __builtin_bit_cast(bf8_t, qfl[c]),     s0a, 0, 0, 0);
                s0b = __builtin_amdgcn_mfma_f32_16x16x32_bf16(kf0[c + 1], __builtin_bit_cast(bf8_t, qfl[c + 1]), s0b, 0, 0, 0);
            }
            #pragma unroll
            for (int c = 0; c < 8; c += 2) {
                s1a = __builtin_amdgcn_mfma_f32_16x16x32_bf16(kf1[c],     __builtin_bit_cast(bf8_t, qfh[c]),     s1a, 0, 0, 0);
                s1b = __builtin_amdgcn_mfma_f32_16x16x32_bf16(kf1[c + 1], __builtin_bit_cast(bf8_t, qfh[c + 1]), s1b, 0, 0, 0);
                s1a = __builtin_amdgcn_mfma_f32_16x16x32_bf16(kf1[c],     __builtin_bit_cast(bf8_t, qfl[c]),     s1a, 0, 0, 0);
                s1b = __builtin_amdgcn_mfma_f32_16x16x32_bf16(kf1[c + 1], __builtin_bit_cast(bf8_t, qfl[c + 1]), s1b, 0, 0, 0);
            }
            f4_t sc[2];
            sc[0] = s0a + s0b;
            sc[1] = s1a + s1b;

            // causal mask + per-lane softmax over 8 keys, quad-pair reduce
            float pv[2][4];
            float tm = -1e30f;
            #pragma unroll
            for (int t = 0; t < 2; t++)
                #pragma unroll
                for (int rr = 0; rr < 4; rr++) {
                    int key = kBase + t * 16 + quad * 4 + rr;
                    float sv = (key <= q_g) ? sc[t][rr] : -1e30f;
                    sc[t][rr] = sv;
                    tm = fmaxf(tm, sv);
                }
            tm = fmaxf(tm, __shfl_xor(tm, 16));
            tm = fmaxf(tm, __shfl_xor(tm, 32));
            bool grow = __any(tm > mrun);      // alpha==1 exactly if false
            float mnew = fmaxf(mrun, tm);
            float alpha = grow ? __expf(mrun - mnew) : 1.0f;
            mrun = mnew;
            float ts = 0.f;
            #pragma unroll
            for (int t = 0; t < 2; t++)
                #pragma unroll
                for (int rr = 0; rr < 4; rr++) {
                    float p = __expf(sc[t][rr] - mnew);
                    pv[t][rr] = p;
                    ts += p;
                }
            ts += __shfl_xor(ts, 16);
            ts += __shfl_xor(ts, 32);
            lrun = lrun * alpha + ts;

            // P write before O-rescale: LDS round-trip hides under the muls
            #pragma unroll
            for (int t = 0; t < 2; t++) {
                union { unsigned short us[4]; unsigned long long uu; } pk;
                #pragma unroll
                for (int rr = 0; rr < 4; rr++) pk.us[rr] = f2bf(pv[t][rr]);
                *reinterpret_cast<unsigned long long*>(&Pw[l16 * 40 + t * 16 + quad * 4]) = pk.uu;
            }
            // V batch B
            bf8_t vfB[8];
            #pragma unroll
            for (int dt = 0; dt < 8; dt++)
                vfB[dt] = *reinterpret_cast<const bf8_t*>(vpb + (8 + dt) * 512);
            if (grow) {
                #pragma unroll
                for (int dt = 0; dt < 16; dt++) acc[dt] *= alpha;
            }
            asm volatile("s_waitcnt lgkmcnt(0)" ::: "memory");
            bf8_t pf = *reinterpret_cast<const bf8_t*>(&Pw[l16 * 40 + quad * 8]);
            #pragma unroll
            for (int dt = 0; dt < 8; dt++)
                acc[dt] = __builtin_amdgcn_mfma_f32_16x16x32_bf16(vfA[dt], pf, acc[dt], 0, 0, 0);
            #pragma unroll
            for (int dt = 0; dt < 8; dt++)
                acc[8 + dt] = __builtin_amdgcn_mfma_f32_16x16x32_bf16(vfB[dt], pf, acc[8 + dt], 0, 0, 0);
        }

        asm volatile("s_waitcnt vmcnt(0)" ::: "memory");
        __syncthreads();
    }

    float inv = 1.f / lrun;
    float* dst = hout + hb + (size_t)q_g * D + quad * 4;
    #pragma unroll
    for (int dt = 0; dt < 16; dt++) {
        float4 o = {acc[dt][0] * inv, acc[dt][1] * inv,
                    acc[dt][2] * inv, acc[dt][3] * inv};
        *reinterpret_cast<float4*>(dst + dt * 16) = o;
    }
}

// ---------------- equivariant path: one wave per q row ---------------------
__global__ __launch_bounds__(256) void equiv_kernel(
    const float* __restrict__ xsb, float* __restrict__ xout)
{
    __shared__ float xs[L * NCH];
    int head = blockIdx.y;
    int tid = threadIdx.x;
    const float4* src = reinterpret_cast<const float4*>(xsb + (size_t)head * L * NCH);
    #pragma unroll
    for (int it = 0; it < 3; it++)
        reinterpret_cast<float4*>(xs)[tid + it * 256] = src[tid + it * 256];
    __syncthreads();

    int w = tid >> 6, lane = tid & 63;
    int q = blockIdx.x * 4 + w;
    float xq0 = xs[q * 3 + 0], xq1 = xs[q * 3 + 1], xq2 = xs[q * 3 + 2];

    float m = 0.f;
    for (int k = lane; k < q; k += 64) {
        float d0 = xq0 - xs[k * 3 + 0];
        float d1 = xq1 - xs[k * 3 + 1];
        float d2 = xq2 - xs[k * 3 + 2];
        m = fmaxf(m, d0 * d0 + d1 * d1 + d2 * d2);
    }
    #pragma unroll
    for (int off = 1; off < 64; off <<= 1) m = fmaxf(m, __shfl_xor(m, off));

    float s0 = 0.f, s1 = 0.f, s2 = 0.f, sn = 0.f;
    for (int k = lane; k < q; k += 64) {
        float d0 = xq0 - xs[k * 3 + 0];
        float d1 = xq1 - xs[k * 3 + 1];
        float d2 = xq2 - xs[k * 3 + 2];
        float wgt = __expf(d0 * d0 + d1 * d1 + d2 * d2 - m);
        sn += wgt;
        s0 += wgt * xs[k * 3 + 0];
        s1 += wgt * xs[k * 3 + 1];
        s2 += wgt * xs[k * 3 + 2];
    }
    #pragma unroll
    for (int off = 1; off < 64; off <<= 1) {
        sn += __shfl_xor(sn, off);
        s0 += __shfl_xor(s0, off);
        s1 += __shfl_xor(s1, off);
        s2 += __shfl_xor(s2, off);
    }
    float Z = sn + __expf(-m);
    float inv = 0.5f / Z;
    if (lane == 0) {
        size_t ob = (size_t)head * L * NCH + (size_t)q * NCH;
        xout[ob + 0] = xq0 + inv * (s0 - sn * xq0);
        xout[ob + 1] = xq1 + inv * (s1 - sn * xq1);
        xout[ob + 2] = xq2 + inv * (s2 - sn * xq2);
    }
}

extern "C" void kernel_launch(void* const* d_in, const int* in_sizes, int n_in,
                              void* d_out, int out_size, void* d_ws, size_t ws_size,
                              hipStream_t stream)
{
    (void)in_sizes; (void)n_in; (void)out_size; (void)ws_size;
    const float* theta = (const float*)d_in[0];
    const float* xi    = (const float*)d_in[1];
    const float* edge  = (const float*)d_in[2];
    const float* Wq    = (const float*)d_in[3];
    const float* Wk    = (const float*)d_in[4];
    const float* Wv    = (const float*)d_in[5];

    float* out  = (float*)d_out;
    float* hout = out;
    float* xout = out + 8388608;
    float* eout = out + 8388608 + 98304;

    const size_t NE = 8388608;
    unsigned short* base = (unsigned short*)d_ws;
    unsigned short* qh  = base;
    unsigned short* ql  = base + NE;
    unsigned short* kh  = base + 2 * NE;
    unsigned short* vt  = base + 3 * NE;
    unsigned short* whb = base + 4 * NE;                   // 196608 us
    float* pe_d = (float*)(base + 4 * NE + 196608);        // 1024*256 floats
    float* xsb  = pe_d + L * D;                            // 32*1024*3 floats

    prep_kernel<<<3296, 256, 0, stream>>>(edge, xi, Wq, Wk, Wv, pe_d, eout, xsb, whb);
    equiv_kernel<<<dim3(L / 4, HEADS), 256, 0, stream>>>(xsb, xout);
    qkv_mfma<<<768, 256, 0, stream>>>(theta, pe_d, whb, qh, ql, kh, vt);
    attn_v7<<<256, 512, 0, stream>>>(qh, ql, kh, vt, hout);
}

// Round 8
// 230.606 us; speedup vs baseline: 1.2306x; 1.0645x over previous
//
#include <hip/hip_runtime.h>
#include <math.h>

#define L    1024
#define D    256
#define NCH  3
#define HEADS 32      // B*N
#define EDIM 112
#define BATCH 4

typedef __bf16 bf8_t __attribute__((ext_vector_type(8)));
typedef float  f4_t  __attribute__((ext_vector_type(4)));

typedef __attribute__((address_space(1))) const void GVC;
typedef __attribute__((address_space(3))) void LDSV;

// RNE float->bf16
__device__ inline unsigned short f2bf(float x) {
    unsigned u = __float_as_uint(x);
    u += 0x7FFFu + ((u >> 16) & 1u);
    return (unsigned short)(u >> 16);
}
__device__ inline float bf2f(unsigned short h) {
    return __uint_as_float(((unsigned)h) << 16);
}

// ------- fused prologue: pe_d table + edge + xs + whb (frag-major bf16) ----
__global__ void prep_kernel(const float* __restrict__ edge, const float* __restrict__ xi,
                            const float* __restrict__ Wq, const float* __restrict__ Wk,
                            const float* __restrict__ Wv,
                            float* __restrict__ pe_d, float* __restrict__ eout,
                            float* __restrict__ xsb, unsigned short* __restrict__ whb)
{
    int idx = blockIdx.x * blockDim.x + threadIdx.x;
    if (idx < L * D) {
        int l = idx >> 8, i = idx & (D - 1);
        float expo = (float)(i & ~1) * (1.0f / (float)D);
        float ang = (float)l * __powf(10000.0f, -expo);
        pe_d[idx] = (i & 1) ? cosf(ang) : sinf(ang);
    } else if (idx < L * D + BATCH * L * EDIM) {
        int j = idx - L * D;
        int i = j % EDIM;
        int l = (j / EDIM) % L;
        float expo = (float)(i & ~1) * (1.0f / (float)EDIM);
        float ang = (float)l * __powf(10000.0f, -expo);
        eout[j] = edge[j] + ((i & 1) ? cosf(ang) : sinf(ang));
    } else if (idx < L * D + BATCH * L * EDIM + HEADS * L * NCH) {
        int j = idx - (L * D + BATCH * L * EDIM);
        int c = j % 3;
        int l = (j / 3) & (L - 1);
        float ang = (c == 2) ? (float)l * 0.0021544347f : (float)l;  // 10000^(-2/3)
        float pe = (c == 1) ? cosf(ang) : sinf(ang);
        xsb[j] = xi[j] + pe;
    } else {
        int j = idx - (L * D + BATCH * L * EDIM + HEADS * L * NCH);
        if (j < 3 * 8192) {                       // W -> bf16, fragment-major
            int wsel = j >> 13;
            int t = j & 8191;
            int g = t >> 9, u = (t >> 4) & 31, rr = t & 15;
            const float* W = (wsel == 0) ? Wq : (wsel == 1) ? Wk : Wv;
            const float4* s = reinterpret_cast<const float4*>(&W[(size_t)(g * 16 + rr) * D + u * 8]);
            float4 a = s[0], b = s[1];
            float x[8] = {a.x, a.y, a.z, a.w, b.x, b.y, b.z, b.w};
            union { unsigned short us[8]; float4 f4; } hv;
            #pragma unroll
            for (int q = 0; q < 8; q++) hv.us[q] = f2bf(x[q]);
            *reinterpret_cast<float4*>(&whb[(size_t)wsel * 65536 + g * 4096 + u * 128 + rr * 8]) = hv.f4;
        }
    }
}

// ---------------- QKV projection: 8-wave blocks, top-issued staging --------
// R7 diagnosis: 4-wave blocks at ~1 resident block/CU + stageW issued at the
// BOTTOM of each iteration (full exposed L2 latency before the barrier drain)
// -> ~8k cyc/kt, MfmaUtil 12%, Occupancy 8.9%. v8: 512 threads (8 waves,
// wave = e-half x x-quarter, acc 16 frags = 64 VGPR), stageW + next-theta
// loads issued at the TOP of each iteration (a full MFMA phase covers their
// latency), conversion overlaps MFMA. Same fragment-major LDS + pre-swizzled
// kh/vt contracts for attn.
__global__ __launch_bounds__(512) void qkv_mfma(
    const float* __restrict__ theta, const float* __restrict__ pe_d,
    const unsigned short* __restrict__ whb,
    unsigned short* __restrict__ qh, unsigned short* __restrict__ ql,
    unsigned short* __restrict__ kh, unsigned short* __restrict__ vt)
{
    __shared__ __align__(16) unsigned short XsH[2][4096];  // 16KB X-hi dbuf
    __shared__ __align__(16) unsigned short XsL[2][4096];  // 16KB X-lo dbuf
    __shared__ __align__(16) unsigned short Ws[2][8192];   // 32KB W dbuf

    int tid = threadIdx.x;
    int w = tid >> 6, lane = tid & 63;
    int quad = lane >> 4, l16 = lane & 15;
    int eh = w & 1;                     // e-half: frags eh*8..eh*8+7
    int xq = w >> 1;                    // x-quarter: frags xq*2, xq*2+1

    int b = blockIdx.x;                 // 0..767
    int xcd = b & 7, r = b >> 3;        // r 0..95
    int wsel = r % 3;
    int panel = (r / 3) * 8 + xcd;      // all 3 wsel of a panel share an XCD
    int rowBase = panel * 128;
    const unsigned short* wsrc = whb + (size_t)wsel * 65536;

    // conversion slot: thread -> (row sr, 8-elem k-unit) of the 128x32 X tile
    int sr = tid >> 2;                  // 0..127
    int ks8 = (tid & 3) * 8;            // 0,8,16,24
    int cg = sr >> 4, cr = sr & 15, cu = tid & 3;
    int xoff = cg * 512 + cu * 128 + cr * 8;     // fragment-major elem offset

    const float* tp_base = &theta[(size_t)(rowBase + sr) * D + ks8];
    const float* pp_base = &pe_d[(size_t)((rowBase + sr) & (L - 1)) * D + ks8];

    f4_t acc[16];
    #pragma unroll
    for (int i = 0; i < 16; i++) acc[i] = (f4_t){0.f, 0.f, 0.f, 0.f};

    auto stageW = [&](int kt, int buf) {
        #pragma unroll
        for (int j = 0; j < 2; j++) {
            int g = w * 2 + j;          // wave-uniform chunk id, 0..15
            __builtin_amdgcn_global_load_lds(
                (GVC*)(wsrc + (size_t)g * 4096 + kt * 512 + lane * 8),
                (LDSV*)(Ws[buf] + g * 512), 16, 0, 0);
        }
    };
    auto loadX = [&](int kt, float* xv) {
        const float* tp = tp_base + kt * 32;
        const float* pp = pp_base + kt * 32;
        float4 t0 = reinterpret_cast<const float4*>(tp)[0];
        float4 t1 = reinterpret_cast<const float4*>(tp)[1];
        float4 p0 = reinterpret_cast<const float4*>(pp)[0];
        float4 p1 = reinterpret_cast<const float4*>(pp)[1];
        xv[0] = t0.x + p0.x; xv[1] = t0.y + p0.y; xv[2] = t0.z + p0.z; xv[3] = t0.w + p0.w;
        xv[4] = t1.x + p1.x; xv[5] = t1.y + p1.y; xv[6] = t1.z + p1.z; xv[7] = t1.w + p1.w;
    };
    auto convX = [&](const float* xv, int buf) {
        union { unsigned short us[8]; float4 f4; } h, lo;
        #pragma unroll
        for (int e = 0; e < 8; e++) {
            unsigned short hh = f2bf(xv[e]);
            h.us[e] = hh;
            lo.us[e] = f2bf(xv[e] - bf2f(hh));
        }
        *reinterpret_cast<float4*>(&XsH[buf][xoff]) = h.f4;
        *reinterpret_cast<float4*>(&XsL[buf][xoff]) = lo.f4;
    };

    // prologue: tile 0
    {
        float xv[8];
        loadX(0, xv);
        convX(xv, 0);
        stageW(0, 0);
    }
    __syncthreads();

    #define FR(buf2d, g16) (*reinterpret_cast<const bf8_t*>(&(buf2d)[(g16) * 512 + quad * 128 + l16 * 8]))

    for (int kt = 0; kt < 8; kt++) {
        int buf = kt & 1;

        // next-tile staging issued FIRST: full MFMA phase covers the latency
        float xn[8];
        if (kt < 7) {
            stageW(kt + 1, buf ^ 1);
            loadX(kt + 1, xn);
        }
        __builtin_amdgcn_sched_barrier(0);

        bf8_t bxh[2], bxl[2];
        #pragma unroll
        for (int nx = 0; nx < 2; nx++) {
            bxh[nx] = FR(XsH[buf], xq * 2 + nx);
            bxl[nx] = FR(XsL[buf], xq * 2 + nx);
        }

        if (wsel < 2) {
            #pragma unroll
            for (int ne = 0; ne < 8; ne++) {
                bf8_t aw = FR(Ws[buf], eh * 8 + ne);
                #pragma unroll
                for (int nx = 0; nx < 2; nx++) {
                    acc[ne * 2 + nx] = __builtin_amdgcn_mfma_f32_16x16x32_bf16(aw, bxh[nx], acc[ne * 2 + nx], 0, 0, 0);
                    acc[ne * 2 + nx] = __builtin_amdgcn_mfma_f32_16x16x32_bf16(aw, bxl[nx], acc[ne * 2 + nx], 0, 0, 0);
                }
            }
        } else {
            #pragma unroll
            for (int ne = 0; ne < 8; ne++) {
                bf8_t bw = FR(Ws[buf], eh * 8 + ne);
                #pragma unroll
                for (int mx = 0; mx < 2; mx++) {
                    acc[mx * 8 + ne] = __builtin_amdgcn_mfma_f32_16x16x32_bf16(bxh[mx], bw, acc[mx * 8 + ne], 0, 0, 0);
                    acc[mx * 8 + ne] = __builtin_amdgcn_mfma_f32_16x16x32_bf16(bxl[mx], bw, acc[mx * 8 + ne], 0, 0, 0);
                }
            }
        }

        if (kt < 7) convX(xn, buf ^ 1);  // VALU; overlaps MFMA pipe tail
        __syncthreads();
    }
    #undef FR

    // ---- epilogue ----
    if (wsel < 2) {
        float scale = (wsel == 0) ? 0.0625f : 1.0f;  // fold 1/sqrt(d) into q
        #pragma unroll
        for (int ne = 0; ne < 8; ne++) {
            #pragma unroll
            for (int nx = 0; nx < 2; nx++) {
                int e0 = eh * 128 + ne * 16 + quad * 4;
                size_t row = rowBase + xq * 32 + nx * 16 + l16;
                union { unsigned short us[4]; unsigned long long u; } ph, pl;
                #pragma unroll
                for (int rr = 0; rr < 4; rr++) {
                    float x = acc[ne * 2 + nx][rr] * scale;
                    unsigned short h = f2bf(x);
                    ph.us[rr] = h;
                    pl.us[rr] = f2bf(x - bf2f(h));
                }
                if (wsel == 0) {
                    *reinterpret_cast<unsigned long long*>(&qh[row * D + e0]) = ph.u;
                    *reinterpret_cast<unsigned long long*>(&ql[row * D + e0]) = pl.u;
                } else {
                    int e0s = e0 ^ ((l16 & 7) << 3);   // row&7 == l16&7
                    *reinterpret_cast<unsigned long long*>(&kh[row * D + e0s]) = ph.u;
                }
            }
        }
    } else {
        #pragma unroll
        for (int mx = 0; mx < 2; mx++) {
            #pragma unroll
            for (int ne = 0; ne < 8; ne++) {
                int row0 = rowBase + xq * 32 + mx * 16 + quad * 4;
                int e = eh * 128 + ne * 16 + l16;
                int head = row0 >> 10, kb = (row0 & 1023) >> 5, kk = row0 & 31;
                union { unsigned short us[4]; unsigned long long u; } pk;
                #pragma unroll
                for (int rr = 0; rr < 4; rr++) pk.us[rr] = f2bf(acc[mx * 8 + ne][rr]);
                int us_sw = (e * 32 + kk) ^ (((e >> 1) & 3) << 3);  // V-tile swizzle
                *reinterpret_cast<unsigned long long*>(
                    &vt[((size_t)(head * 32 + kb)) * 8192 + us_sw]) = pk.u;
            }
        }
    }
}

// ---------------- LDS-shared MFMA flash attention --------------------------
// Block (head,s): 8 mirrored units {4s..4s+3, 63-4s..60-4s}; stages
// Ts = 32-2s K/V tiles via global_load_lds (double-buffered), shared by all
// 8 waves -> fabric traffic /5 vs per-wave fetch. (R4: confirmed, ~110->~40us)
__device__ __forceinline__ void stage_tile(
    const unsigned short* kht, const unsigned short* vtt,
    unsigned short* Ks, unsigned short* Vs, int kt, int buf, int w, int lane)
{
    #pragma unroll
    for (int i = 0; i < 2; i++) {
        int ch = w * 2 + i;   // wave-uniform chunk id (LDS base must be uniform)
        __builtin_amdgcn_global_load_lds(
            (GVC*)(kht + (size_t)kt * 8192 + ch * 512 + lane * 8),
            (LDSV*)(Ks + buf * 8192 + ch * 512), 16, 0, 0);
        __builtin_amdgcn_global_load_lds(
            (GVC*)(vtt + (size_t)kt * 8192 + ch * 512 + lane * 8),
            (LDSV*)(Vs + buf * 8192 + ch * 512), 16, 0, 0);
    }
}

__global__ __launch_bounds__(512) void attn_v7(
    const unsigned short* __restrict__ qh, const unsigned short* __restrict__ ql,
    const unsigned short* __restrict__ kh, const unsigned short* __restrict__ vt,
    float* __restrict__ hout)
{
    __shared__ __align__(16) unsigned short Ks[2 * 8192];   // 32KB K dbuf
    __shared__ __align__(16) unsigned short Vs[2 * 8192];   // 32KB V dbuf
    __shared__ __align__(16) unsigned short Pb[8][16 * 40]; // 10KB P
    __shared__ unsigned short lds_pad[4200];                // >80KB: 1 block/CU

    int tid = threadIdx.x;
    int w = tid >> 6, lane = tid & 63;
    int quad = lane >> 4, l16 = lane & 15;
    int b = blockIdx.x;
    int head = ((b & 7) << 2) + (b >> 6);     // 4 heads per XCD share L2
    int s = (b >> 3) & 7;
    int u = (w < 4) ? (4 * s + w) : (63 - 4 * s - (w - 4));  // mirrored units
    int Ts = 32 - 2 * s;
    int lim = u >> 1;
    size_t hb = (size_t)head * (L * D);
    const unsigned short* kht = kh + hb;
    const unsigned short* vtt = vt + (size_t)head * (32 * 8192);
    unsigned short* Pw = Pb[w];

    if (hout == nullptr) lds_pad[tid] = 1;    // opaque: keep pad allocated

    int q_g = u * 16 + l16;

    // Q fragments in registers for the whole kernel; asm keep-alive stops
    // the scheduler from sinking/re-fetching them inside the k-loop.
    f4_t qfh[8], qfl[8];
    {
        const unsigned short* ph = qh + hb + (size_t)q_g * D + quad * 8;
        const unsigned short* pl = ql + hb + (size_t)q_g * D + quad * 8;
        #pragma unroll
        for (int c = 0; c < 8; c++) {
            qfh[c] = *reinterpret_cast<const f4_t*>(ph + c * 32);
            qfl[c] = *reinterpret_cast<const f4_t*>(pl + c * 32);
        }
    }
    #pragma unroll
    for (int c = 0; c < 8; c++) {
        asm volatile("" : "+v"(qfh[c]));
        asm volatile("" : "+v"(qfl[c]));
    }

    stage_tile(kht, vtt, Ks, Vs, 0, 0, w, lane);

    f4_t acc[16];
    #pragma unroll
    for (int i = 0; i < 16; i++) acc[i] = (f4_t){0.f, 0.f, 0.f, 0.f};
    float mrun = -1e30f, lrun = 0.f;

    int xm = (l16 & 7) << 3;                        // K e-swizzle (us)
    int vq = (quad * 8) ^ (((l16 >> 1) & 3) << 3);  // V swizzled col base

    asm volatile("s_waitcnt vmcnt(0)" ::: "memory");
    __syncthreads();

    #pragma unroll 1
    for (int kt = 0; kt < Ts; kt++) {
        if (kt + 1 < Ts)
            stage_tile(kht, vtt, Ks, Vs, kt + 1, (kt + 1) & 1, w, lane);

        if (kt <= lim) {   // wave-uniform predicate
            const unsigned short* Kb = Ks + (kt & 1) * 8192;
            const unsigned short* Vb = Vs + (kt & 1) * 8192;
            int kBase = kt * 32;

            bf8_t kf0[8], kf1[8];
            #pragma unroll
            for (int c = 0; c < 8; c++) {
                int col = (quad * 8 + c * 32) ^ xm;
                kf0[c] = *reinterpret_cast<const bf8_t*>(&Kb[l16 * 256 + col]);
                kf1[c] = *reinterpret_cast<const bf8_t*>(&Kb[(16 + l16) * 256 + col]);
            }
            // V batch A: LDS-read latency hides under the QK MFMAs
            const unsigned short* vpb = Vb + l16 * 32 + vq;
            bf8_t vfA[8];
            #pragma unroll
            for (int dt = 0; dt < 8; dt++)
                vfA[dt] = *reinterpret_cast<const bf8_t*>(vpb + dt * 512);

            // dual accumulator chains: halves dependent-MFMA depth
            f4_t s0a = (f4_t){0.f,0.f,0.f,0.f}, s0b = (f4_t){0.f,0.f,0.f,0.f};
            f4_t s1a = (f4_t){0.f,0.f,0.f,0.f}, s1b = (f4_t){0.f,0.f,0.f,0.f};
            #pragma unroll
            for (int c = 0; c < 8; c += 2) {
                s0a = __builtin_amdgcn_mfma_f32_16x16x32_bf16(kf0[c],     __builtin_bit_cast(bf8_t, qfh[c]),     s0a, 0, 0, 0);
                s0b = __builtin_amdgcn_mfma_f32_16x16x32_bf16(kf0[c + 1], __builtin_bit_cast(bf8_t, qfh[c + 1]), s0b, 0, 0, 0);
                s0a = __builtin_amdgcn_mfma_f32_16x16x32_bf16(kf0[c],     __builtin_bit_cast(bf8_t, qfl[c]),     s0a, 0, 0, 0);
                s0b = __builtin_amdgcn_mfma_f32_16x16x32_bf16(kf0[c + 1], __builtin_bit_cast(bf8_t, qfl[c + 1]), s0b, 0, 0, 0);
            }
            #pragma unroll
            for (int c = 0; c < 8; c += 2) {
                s1a = __builtin_amdgcn_mfma_f32_16x16x32_bf16(kf1[c],     __builtin_bit_cast(bf8_t, qfh[c]),     s1a, 0, 0, 0);
                s1b = __builtin_amdgcn_mfma_f32_16x16x32_bf16(kf1[c + 1], __builtin_bit_cast(bf8_t, qfh[c + 1]), s1b, 0, 0, 0);
                s1a = __builtin_amdgcn_mfma_f32_16x16x32_bf16(kf1[c],     __builtin_bit_cast(bf8_t, qfl[c]),     s1a, 0, 0, 0);
                s1b = __builtin_amdgcn_mfma_f32_16x16x32_bf16(kf1[c + 1], __builtin_bit_cast(bf8_t, qfl[c + 1]), s1b, 0, 0, 0);
            }
            f4_t sc[2];
            sc[0] = s0a + s0b;
            sc[1] = s1a + s1b;

            // causal mask + per-lane softmax over 8 keys, quad-pair reduce
            float pv[2][4];
            float tm = -1e30f;
            #pragma unroll
            for (int t = 0; t < 2; t++)
                #pragma unroll
                for (int rr = 0; rr < 4; rr++) {
                    int key = kBase + t * 16 + quad * 4 + rr;
                    float sv = (key <= q_g) ? sc[t][rr] : -1e30f;
                    sc[t][rr] = sv;
                    tm = fmaxf(tm, sv);
                }
            tm = fmaxf(tm, __shfl_xor(tm, 16));
            tm = fmaxf(tm, __shfl_xor(tm, 32));
            bool grow = __any(tm > mrun);      // alpha==1 exactly if false
            float mnew = fmaxf(mrun, tm);
            float alpha = grow ? __expf(mrun - mnew) : 1.0f;
            mrun = mnew;
            float ts = 0.f;
            #pragma unroll
            for (int t = 0; t < 2; t++)
                #pragma unroll
                for (int rr = 0; rr < 4; rr++) {
                    float p = __expf(sc[t][rr] - mnew);
                    pv[t][rr] = p;
                    ts += p;
                }
            ts += __shfl_xor(ts, 16);
            ts += __shfl_xor(ts, 32);
            lrun = lrun * alpha + ts;

            // P write before O-rescale: LDS round-trip hides under the muls
            #pragma unroll
            for (int t = 0; t < 2; t++) {
                union { unsigned short us[4]; unsigned long long uu; } pk;
                #pragma unroll
                for (int rr = 0; rr < 4; rr++) pk.us[rr] = f2bf(pv[t][rr]);
                *reinterpret_cast<unsigned long long*>(&Pw[l16 * 40 + t * 16 + quad * 4]) = pk.uu;
            }
            // V batch B
            bf8_t vfB[8];
            #pragma unroll
            for (int dt = 0; dt < 8; dt++)
                vfB[dt] = *reinterpret_cast<const bf8_t*>(vpb + (8 + dt) * 512);
            if (grow) {
                #pragma unroll
                for (int dt = 0; dt < 16; dt++) acc[dt] *= alpha;
            }
            asm volatile("s_waitcnt lgkmcnt(0)" ::: "memory");
            bf8_t pf = *reinterpret_cast<const bf8_t*>(&Pw[l16 * 40 + quad * 8]);
            #pragma unroll
            for (int dt = 0; dt < 8; dt++)
                acc[dt] = __builtin_amdgcn_mfma_f32_16x16x32_bf16(vfA[dt], pf, acc[dt], 0, 0, 0);
            #pragma unroll
            for (int dt = 0; dt < 8; dt++)
                acc[8 + dt] = __builtin_amdgcn_mfma_f32_16x16x32_bf16(vfB[dt], pf, acc[8 + dt], 0, 0, 0);
        }

        asm volatile("s_waitcnt vmcnt(0)" ::: "memory");
        __syncthreads();
    }

    float inv = 1.f / lrun;
    float* dst = hout + hb + (size_t)q_g * D + quad * 4;
    #pragma unroll
    for (int dt = 0; dt < 16; dt++) {
        float4 o = {acc[dt][0] * inv, acc[dt][1] * inv,
                    acc[dt][2] * inv, acc[dt][3] * inv};
        *reinterpret_cast<float4*>(dst + dt * 16) = o;
    }
}

// ---------------- equivariant path: one wave per q row ---------------------
__global__ __launch_bounds__(256) void equiv_kernel(
    const float* __restrict__ xsb, float* __restrict__ xout)
{
    __shared__ float xs[L * NCH];
    int head = blockIdx.y;
    int tid = threadIdx.x;
    const float4* src = reinterpret_cast<const float4*>(xsb + (size_t)head * L * NCH);
    #pragma unroll
    for (int it = 0; it < 3; it++)
        reinterpret_cast<float4*>(xs)[tid + it * 256] = src[tid + it * 256];
    __syncthreads();

    int w = tid >> 6, lane = tid & 63;
    int q = blockIdx.x * 4 + w;
    float xq0 = xs[q * 3 + 0], xq1 = xs[q * 3 + 1], xq2 = xs[q * 3 + 2];

    float m = 0.f;
    for (int k = lane; k < q; k += 64) {
        float d0 = xq0 - xs[k * 3 + 0];
        float d1 = xq1 - xs[k * 3 + 1];
        float d2 = xq2 - xs[k * 3 + 2];
        m = fmaxf(m, d0 * d0 + d1 * d1 + d2 * d2);
    }
    #pragma unroll
    for (int off = 1; off < 64; off <<= 1) m = fmaxf(m, __shfl_xor(m, off));

    float s0 = 0.f, s1 = 0.f, s2 = 0.f, sn = 0.f;
    for (int k = lane; k < q; k += 64) {
        float d0 = xq0 - xs[k * 3 + 0];
        float d1 = xq1 - xs[k * 3 + 1];
        float d2 = xq2 - xs[k * 3 + 2];
        float wgt = __expf(d0 * d0 + d1 * d1 + d2 * d2 - m);
        sn += wgt;
        s0 += wgt * xs[k * 3 + 0];
        s1 += wgt * xs[k * 3 + 1];
        s2 += wgt * xs[k * 3 + 2];
    }
    #pragma unroll
    for (int off = 1; off < 64; off <<= 1) {
        sn += __shfl_xor(sn, off);
        s0 += __shfl_xor(s0, off);
        s1 += __shfl_xor(s1, off);
        s2 += __shfl_xor(s2, off);
    }
    float Z = sn + __expf(-m);
    float inv = 0.5f / Z;
    if (lane == 0) {
        size_t ob = (size_t)head * L * NCH + (size_t)q * NCH;
        xout[ob + 0] = xq0 + inv * (s0 - sn * xq0);
        xout[ob + 1] = xq1 + inv * (s1 - sn * xq1);
        xout[ob + 2] = xq2 + inv * (s2 - sn * xq2);
    }
}

extern "C" void kernel_launch(void* const* d_in, const int* in_sizes, int n_in,
                              void* d_out, int out_size, void* d_ws, size_t ws_size,
                              hipStream_t stream)
{
    (void)in_sizes; (void)n_in; (void)out_size; (void)ws_size;
    const float* theta = (const float*)d_in[0];
    const float* xi    = (const float*)d_in[1];
    const float* edge  = (const float*)d_in[2];
    const float* Wq    = (const float*)d_in[3];
    const float* Wk    = (const float*)d_in[4];
    const float* Wv    = (const float*)d_in[5];

    float* out  = (float*)d_out;
    float* hout = out;
    float* xout = out + 8388608;
    float* eout = out + 8388608 + 98304;

    const size_t NE = 8388608;
    unsigned short* base = (unsigned short*)d_ws;
    unsigned short* qh  = base;
    unsigned short* ql  = base + NE;
    unsigned short* kh  = base + 2 * NE;
    unsigned short* vt  = base + 3 * NE;
    unsigned short* whb = base + 4 * NE;                   // 196608 us
    float* pe_d = (float*)(base + 4 * NE + 196608);        // 1024*256 floats
    float* xsb  = pe_d + L * D;                            // 32*1024*3 floats

    prep_kernel<<<3296, 256, 0, stream>>>(edge, xi, Wq, Wk, Wv, pe_d, eout, xsb, whb);
    equiv_kernel<<<dim3(L / 4, HEADS), 256, 0, stream>>>(xsb, xout);
    qkv_mfma<<<768, 512, 0, stream>>>(theta, pe_d, whb, qh, ql, kh, vt);
    attn_v7<<<256, 512, 0, stream>>>(qh, ql, kh, vt, hout);
}